// Round 1
// baseline (514.643 us; speedup 1.0000x reference)
//
#include <hip/hip_runtime.h>
#include <math.h>

#define HH 256
#define WW 256
#define NB 16
#define NC 32
#define RAD 3
#define KWID 7
#define NTAPS 49
#define TILE 64
#define CW 76      // conv staging region: TILE + 2*6
#define CH 76
#define DW 70      // dilation region: TILE + 2*3
#define DSTR 72    // padded row stride (16B-aligned float4 rows)
#define BIGF 1e30f
#define FLT_MAX_C 3.402823466e+38f

// ---------------- kernel-table generation (49 taps per channel) ----------------
__global__ void kgen_kernel(const float* __restrict__ fd,
                            const float* __restrict__ fe,
                            float* __restrict__ kd,
                            float* __restrict__ ke) {
    const int c = blockIdx.x;
    const int t = threadIdx.x;
    if (t >= NTAPS) return;
    const int dy = t / KWID - RAD;
    const int dx = t % KWID - RAD;
    const double rho = sqrt((double)(dx * dx + dy * dy));
    const double th  = atan2((double)dy, (double)dx);
    const double alpha = 0.65;
    const double p  = 2.0 * alpha / (2.0 * alpha - 1.0);           // 4.3333...
    const double nu = (2.0 * alpha - 1.0) * pow(2.0 * alpha, -p);  // ~0.0962
    const double b1 = cos(th), b2 = sin(th), b3 = cos(2.0 * th), b4 = sin(2.0 * th);
    double s, F;
    s = (double)fd[c * 4 + 0] * b1 + (double)fd[c * 4 + 1] * b2
      + (double)fd[c * 4 + 2] * b3 + (double)fd[c * 4 + 3] * b4;
    F = rho * exp(-s);
    kd[c * NTAPS + t] = (float)(nu * pow(F, p));
    s = (double)fe[c * 4 + 0] * b1 + (double)fe[c * 4 + 1] * b2
      + (double)fe[c * 4 + 2] * b3 + (double)fe[c * 4 + 3] * b4;
    F = rho * exp(-s);
    ke[c * NTAPS + t] = (float)(nu * pow(F, p));
}

// -------- fused convection + dilation + erosion, per (batch, channel, 64x64 tile) --------
__global__ __launch_bounds__(256) void cde_stencil_kernel(
    const float* __restrict__ xin, const float* __restrict__ csh,
    const float* __restrict__ kdil, const float* __restrict__ kero,
    float* __restrict__ uout)
{
    __shared__ float bufC[CH * CW + 8];  // conv values, -BIGF outside image (+slack for OOB f4 reads)
    __shared__ float bufD[DW * DSTR];    // dilation values, +BIGF outside image

    const int tid = threadIdx.x;
    const int tileId = blockIdx.x;
    const int c = blockIdx.y;
    const int b = blockIdx.z;
    const int ty0 = (tileId >> 2) * TILE;
    const int tx0 = (tileId & 3) * TILE;

    const float cx = csh[c * 2 + 0];
    const float cy = csh[c * 2 + 1];
    const float* __restrict__ xb = xin + (((size_t)b * NC + c) << 16);

    // ---- stage 1: convection (constant per-channel bilinear shift, replicate border) ----
    for (int idx = tid; idx < CH * CW; idx += 256) {
        const int row = idx / CW;
        const int col = idx - row * CW;
        const int gy = ty0 - 6 + row;
        const int gx = tx0 - 6 + col;
        float v = -BIGF;  // dilation-stage pad value (pad of -u is +BIG)
        if (gy >= 0 && gy < HH && gx >= 0 && gx < WW) {
            const float fy = (float)gy - cy;
            const float fx = (float)gx - cx;
            const float y0f = floorf(fy);
            const float x0f = floorf(fx);
            const float wy = fy - y0f;
            const float wx = fx - x0f;
            const int y0 = (int)y0f;
            const int x0 = (int)x0f;
            const int y0c = min(max(y0, 0), HH - 1);
            const int y1c = min(y0c + 1, HH - 1);
            const int x0c = min(max(x0, 0), WW - 1);
            const int x1c = min(x0c + 1, WW - 1);
            const float a00 = xb[(y0c << 8) + x0c];
            const float a01 = xb[(y0c << 8) + x1c];
            const float a10 = xb[(y1c << 8) + x0c];
            const float a11 = xb[(y1c << 8) + x1c];
            v = (1.f - wy) * (1.f - wx) * a00 + (1.f - wy) * wx * a01
              + wy * (1.f - wx) * a10 + wy * wx * a11;
        }
        bufC[idx] = v;
    }
    __syncthreads();

    // ---- stage 2: dilation  u1 = max_d (u0[p+d] - k_dil[d])  on 70x70 (+2 junk cols) ----
    if (tid < 252) {  // 18 col-groups (4 wide) x 14 row-strips (5 tall)
        float kd[NTAPS];
        #pragma unroll
        for (int t = 0; t < NTAPS; ++t) kd[t] = kdil[c * NTAPS + t];

        const int g = tid % 18;
        const int strip = tid / 18;
        const int dc0 = g * 4;
        const int dr0 = strip * 5;

        float acc[5][4];
        #pragma unroll
        for (int i = 0; i < 5; ++i)
            #pragma unroll
            for (int j = 0; j < 4; ++j) acc[i][j] = -FLT_MAX_C;

        #pragma unroll
        for (int rr = 0; rr < 11; ++rr) {  // input rows dr0..dr0+10 (C coords)
            const float* rp = &bufC[(dr0 + rr) * CW + dc0];
            const float4 L0 = *reinterpret_cast<const float4*>(rp);
            const float4 L1 = *reinterpret_cast<const float4*>(rp + 4);
            const float4 L2 = *reinterpret_cast<const float4*>(rp + 8);
            const float ld[12] = {L0.x, L0.y, L0.z, L0.w,
                                  L1.x, L1.y, L1.z, L1.w,
                                  L2.x, L2.y, L2.z, L2.w};
            #pragma unroll
            for (int i = 0; i < 5; ++i) {
                const int ky = rr - i;
                if (ky < 0 || ky > 6) continue;
                #pragma unroll
                for (int j = 0; j < 4; ++j) {
                    float m = acc[i][j];
                    #pragma unroll
                    for (int kx = 0; kx < KWID; ++kx)
                        m = fmaxf(m, ld[j + kx] - kd[ky * KWID + kx]);
                    acc[i][j] = m;
                }
            }
        }

        #pragma unroll
        for (int i = 0; i < 5; ++i) {
            const int dr = dr0 + i;
            const int gy = ty0 - 3 + dr;
            const bool rOK = (gy >= 0) && (gy < HH);
            const int gxb = tx0 - 3 + dc0;
            float4 st;
            st.x = (rOK && (gxb + 0) >= 0 && (gxb + 0) < WW) ? acc[i][0] : BIGF;
            st.y = (rOK && (gxb + 1) >= 0 && (gxb + 1) < WW) ? acc[i][1] : BIGF;
            st.z = (rOK && (gxb + 2) >= 0 && (gxb + 2) < WW) ? acc[i][2] : BIGF;
            st.w = (rOK && (gxb + 3) >= 0 && (gxb + 3) < WW) ? acc[i][3] : BIGF;
            *reinterpret_cast<float4*>(&bufD[dr * DSTR + dc0]) = st;
        }
    }
    __syncthreads();

    // ---- stage 3: erosion  out = min_d (u1[p+d] + k_ero[d])  on the 64x64 tile ----
    {
        float ke[NTAPS];
        #pragma unroll
        for (int t = 0; t < NTAPS; ++t) ke[t] = kero[c * NTAPS + t];

        const int g = tid & 15;      // 16 col-groups (4 wide)
        const int strip = tid >> 4;  // 16 row-strips (4 tall)
        const int ec0 = g * 4;
        const int er0 = strip * 4;

        float acc[4][4];
        #pragma unroll
        for (int i = 0; i < 4; ++i)
            #pragma unroll
            for (int j = 0; j < 4; ++j) acc[i][j] = FLT_MAX_C;

        #pragma unroll
        for (int rr = 0; rr < 10; ++rr) {  // D rows er0..er0+9
            const float* rp = &bufD[(er0 + rr) * DSTR + ec0];
            const float4 L0 = *reinterpret_cast<const float4*>(rp);
            const float4 L1 = *reinterpret_cast<const float4*>(rp + 4);
            const float4 L2 = *reinterpret_cast<const float4*>(rp + 8);
            const float ld[12] = {L0.x, L0.y, L0.z, L0.w,
                                  L1.x, L1.y, L1.z, L1.w,
                                  L2.x, L2.y, L2.z, L2.w};
            #pragma unroll
            for (int i = 0; i < 4; ++i) {
                const int ky = rr - i;
                if (ky < 0 || ky > 6) continue;
                #pragma unroll
                for (int j = 0; j < 4; ++j) {
                    float m = acc[i][j];
                    #pragma unroll
                    for (int kx = 0; kx < KWID; ++kx)
                        m = fminf(m, ld[j + kx] + ke[ky * KWID + kx]);
                    acc[i][j] = m;
                }
            }
        }

        float* __restrict__ ob = uout + (((size_t)b * NC + c) << 16);
        #pragma unroll
        for (int i = 0; i < 4; ++i) {
            float4 st;
            st.x = acc[i][0]; st.y = acc[i][1]; st.z = acc[i][2]; st.w = acc[i][3];
            *reinterpret_cast<float4*>(&ob[((ty0 + er0 + i) << 8) + tx0 + ec0]) = st;
        }
    }
}

// ---------------- in-place channel mix: out[b,:,p] = W^T u[b,:,p] ----------------
__global__ __launch_bounds__(256) void mix_kernel(float* u, const float* __restrict__ wmat) {
    const int p = blockIdx.x * 256 + threadIdx.x;  // pixel within image
    const int b = blockIdx.y;
    float* ub = u + ((size_t)b << 21);  // b * 32 * 65536

    float uv[NC];
    #pragma unroll
    for (int i = 0; i < NC; ++i) uv[i] = ub[(i << 16) + p];

    float acc[NC];
    #pragma unroll
    for (int o = 0; o < NC; ++o) acc[o] = 0.f;

    #pragma unroll
    for (int i = 0; i < NC; ++i) {
        const float v = uv[i];
        #pragma unroll
        for (int o = 0; o < NC; ++o)
            acc[o] = fmaf(v, wmat[i * NC + o], acc[o]);  // wave-uniform weight -> s_load
    }

    #pragma unroll
    for (int o = 0; o < NC; ++o) ub[(o << 16) + p] = acc[o];
}

extern "C" void kernel_launch(void* const* d_in, const int* in_sizes, int n_in,
                              void* d_out, int out_size, void* d_ws, size_t ws_size,
                              hipStream_t stream) {
    const float* x  = (const float*)d_in[0];
    const float* c  = (const float*)d_in[1];
    const float* fd = (const float*)d_in[2];
    const float* fe = (const float*)d_in[3];
    const float* w  = (const float*)d_in[4];
    float* out = (float*)d_out;

    float* kd = (float*)d_ws;            // 32*49 floats
    float* ke = kd + NC * NTAPS;         // 32*49 floats (12.5 KB total)

    kgen_kernel<<<dim3(NC), dim3(64), 0, stream>>>(fd, fe, kd, ke);
    cde_stencil_kernel<<<dim3(16, NC, NB), dim3(256), 0, stream>>>(x, c, kd, ke, out);
    mix_kernel<<<dim3((HH * WW) / 256, NB), dim3(256), 0, stream>>>(out, w);
}

// Round 2
// 504.745 us; speedup vs baseline: 1.0196x; 1.0196x over previous
//
#include <hip/hip_runtime.h>
#include <math.h>

#define HH 256
#define WW 256
#define NB 16
#define NC 32
#define RAD 3
#define KWID 7
#define NTAPS 49
#define TILE 64
#define CW 76      // conv staging region: TILE + 2*6
#define CH 76
#define DW 70      // dilation region: TILE + 2*3
#define DSTR 72    // padded row stride for dilation rows (16B-aligned)
#define BUFSZ (CH * CW + 8)   // 5784 floats = 23.1 KB (slack for OOB f4 reads)
#define BIGF 1e30f
#define FLT_MAX_C 3.402823466e+38f

// ---------------- kernel-table generation (49 taps per channel) ----------------
__global__ void kgen_kernel(const float* __restrict__ fd,
                            const float* __restrict__ fe,
                            float* __restrict__ kd,
                            float* __restrict__ ke) {
    const int c = blockIdx.x;
    const int t = threadIdx.x;
    if (t >= NTAPS) return;
    const int dy = t / KWID - RAD;
    const int dx = t % KWID - RAD;
    const double rho = sqrt((double)(dx * dx + dy * dy));
    const double th  = atan2((double)dy, (double)dx);
    const double alpha = 0.65;
    const double p  = 2.0 * alpha / (2.0 * alpha - 1.0);
    const double nu = (2.0 * alpha - 1.0) * pow(2.0 * alpha, -p);
    const double b1 = cos(th), b2 = sin(th), b3 = cos(2.0 * th), b4 = sin(2.0 * th);
    double s, F;
    s = (double)fd[c * 4 + 0] * b1 + (double)fd[c * 4 + 1] * b2
      + (double)fd[c * 4 + 2] * b3 + (double)fd[c * 4 + 3] * b4;
    F = rho * exp(-s);
    kd[c * NTAPS + t] = (float)(nu * pow(F, p));
    s = (double)fe[c * 4 + 0] * b1 + (double)fe[c * 4 + 1] * b2
      + (double)fe[c * 4 + 2] * b3 + (double)fe[c * 4 + 3] * b4;
    F = rho * exp(-s);
    ke[c * NTAPS + t] = (float)(nu * pow(F, p));
}

// -------- fused convection + dilation + erosion, per (batch, channel, 64x64 tile) --------
// Single LDS buffer, reused: stage1 writes conv (76x76, stride 76); stage2 reads it
// into register accumulators; after a barrier the SAME buffer is overwritten with the
// dilation result (70 rows, stride 72); stage3 reads that. LDS = 23.1 KB -> 6 blocks/CU.
__global__ __launch_bounds__(256) void cde_stencil_kernel(
    const float* __restrict__ xin, const float* __restrict__ csh,
    const float* __restrict__ kdil, const float* __restrict__ kero,
    float* __restrict__ uout)
{
    __shared__ float buf[BUFSZ];

    const int tid = threadIdx.x;
    const int tileId = blockIdx.x;
    const int c = blockIdx.y;
    const int b = blockIdx.z;
    const int ty0 = (tileId >> 2) * TILE;
    const int tx0 = (tileId & 3) * TILE;

    const float cx = csh[c * 2 + 0];
    const float cy = csh[c * 2 + 1];
    const float* __restrict__ xb = xin + (((size_t)b * NC + c) << 16);

    // ---- stage 1: convection. Constant per-channel shift => constant bilinear
    // weights and constant integer offset: floor(gy - cy) == gy + floor(-cy) for int gy.
    const float mcx = -cx, mcy = -cy;
    const float fx0 = floorf(mcx), fy0 = floorf(mcy);
    const float wx = mcx - fx0, wy = mcy - fy0;
    const int IX = (int)fx0, IY = (int)fy0;
    const float w00 = (1.f - wy) * (1.f - wx);
    const float w01 = (1.f - wy) * wx;
    const float w10 = wy * (1.f - wx);
    const float w11 = wy * wx;

    for (int idx = tid; idx < CH * CW; idx += 256) {
        const int row = idx / CW;
        const int col = idx - row * CW;
        const int gy = ty0 - 6 + row;
        const int gx = tx0 - 6 + col;
        float v = -BIGF;  // dilation-stage pad value (pad of -u is +BIG)
        if (gy >= 0 && gy < HH && gx >= 0 && gx < WW) {
            const int y0 = min(max(gy + IY, 0), HH - 1);
            const int y1 = min(y0 + 1, HH - 1);
            const int x0 = min(max(gx + IX, 0), WW - 1);
            const int x1 = min(x0 + 1, WW - 1);
            const float a00 = xb[(y0 << 8) + x0];
            const float a01 = xb[(y0 << 8) + x1];
            const float a10 = xb[(y1 << 8) + x0];
            const float a11 = xb[(y1 << 8) + x1];
            v = w00 * a00 + w01 * a01 + w10 * a10 + w11 * a11;
        }
        buf[idx] = v;
    }
    __syncthreads();

    // ---- stage 2: dilation  u1 = max_d (u0[p+d] - k_dil[d])  on 70x70 (+2 junk cols) ----
    float acc2[5][4];
    int dc0 = 0, dr0 = 0;
    const bool act2 = (tid < 252);  // 18 col-groups (4 wide) x 14 row-strips (5 tall)
    if (act2) {
        float kd[NTAPS];
        #pragma unroll
        for (int t = 0; t < NTAPS; ++t) kd[t] = kdil[c * NTAPS + t];

        const int g = tid % 18;
        const int strip = tid / 18;
        dc0 = g * 4;
        dr0 = strip * 5;

        #pragma unroll
        for (int i = 0; i < 5; ++i)
            #pragma unroll
            for (int j = 0; j < 4; ++j) acc2[i][j] = -FLT_MAX_C;

        #pragma unroll
        for (int rr = 0; rr < 11; ++rr) {  // input rows dr0..dr0+10 (C coords)
            const float* rp = &buf[(dr0 + rr) * CW + dc0];
            const float4 L0 = *reinterpret_cast<const float4*>(rp);
            const float4 L1 = *reinterpret_cast<const float4*>(rp + 4);
            const float4 L2 = *reinterpret_cast<const float4*>(rp + 8);
            const float ld[12] = {L0.x, L0.y, L0.z, L0.w,
                                  L1.x, L1.y, L1.z, L1.w,
                                  L2.x, L2.y, L2.z, L2.w};
            #pragma unroll
            for (int i = 0; i < 5; ++i) {
                const int ky = rr - i;
                if (ky < 0 || ky > 6) continue;
                #pragma unroll
                for (int j = 0; j < 4; ++j) {
                    float m = acc2[i][j];
                    #pragma unroll
                    for (int kx = 0; kx < 6; kx += 2)  // pairs -> v_max3
                        m = fmaxf(m, fmaxf(ld[j + kx]     - kd[ky * KWID + kx],
                                           ld[j + kx + 1] - kd[ky * KWID + kx + 1]));
                    m = fmaxf(m, ld[j + 6] - kd[ky * KWID + 6]);
                    acc2[i][j] = m;
                }
            }
        }
    }
    __syncthreads();  // all stage-2 reads of buf complete -> safe to overwrite

    if (act2) {
        #pragma unroll
        for (int i = 0; i < 5; ++i) {
            const int dr = dr0 + i;
            const int gy = ty0 - 3 + dr;
            const bool rOK = (gy >= 0) && (gy < HH);
            const int gxb = tx0 - 3 + dc0;
            float4 st;
            st.x = (rOK && (gxb + 0) >= 0 && (gxb + 0) < WW) ? acc2[i][0] : BIGF;
            st.y = (rOK && (gxb + 1) >= 0 && (gxb + 1) < WW) ? acc2[i][1] : BIGF;
            st.z = (rOK && (gxb + 2) >= 0 && (gxb + 2) < WW) ? acc2[i][2] : BIGF;
            st.w = (rOK && (gxb + 3) >= 0 && (gxb + 3) < WW) ? acc2[i][3] : BIGF;
            *reinterpret_cast<float4*>(&buf[dr * DSTR + dc0]) = st;
        }
    }
    __syncthreads();

    // ---- stage 3: erosion  out = min_d (u1[p+d] + k_ero[d])  on the 64x64 tile ----
    {
        float ke[NTAPS];
        #pragma unroll
        for (int t = 0; t < NTAPS; ++t) ke[t] = kero[c * NTAPS + t];

        const int g = tid & 15;      // 16 col-groups (4 wide)
        const int strip = tid >> 4;  // 16 row-strips (4 tall)
        const int ec0 = g * 4;
        const int er0 = strip * 4;

        float acc[4][4];
        #pragma unroll
        for (int i = 0; i < 4; ++i)
            #pragma unroll
            for (int j = 0; j < 4; ++j) acc[i][j] = FLT_MAX_C;

        #pragma unroll
        for (int rr = 0; rr < 10; ++rr) {  // D rows er0..er0+9
            const float* rp = &buf[(er0 + rr) * DSTR + ec0];
            const float4 L0 = *reinterpret_cast<const float4*>(rp);
            const float4 L1 = *reinterpret_cast<const float4*>(rp + 4);
            const float4 L2 = *reinterpret_cast<const float4*>(rp + 8);
            const float ld[12] = {L0.x, L0.y, L0.z, L0.w,
                                  L1.x, L1.y, L1.z, L1.w,
                                  L2.x, L2.y, L2.z, L2.w};
            #pragma unroll
            for (int i = 0; i < 4; ++i) {
                const int ky = rr - i;
                if (ky < 0 || ky > 6) continue;
                #pragma unroll
                for (int j = 0; j < 4; ++j) {
                    float m = acc[i][j];
                    #pragma unroll
                    for (int kx = 0; kx < 6; kx += 2)  // pairs -> v_min3
                        m = fminf(m, fminf(ld[j + kx]     + ke[ky * KWID + kx],
                                           ld[j + kx + 1] + ke[ky * KWID + kx + 1]));
                    m = fminf(m, ld[j + 6] + ke[ky * KWID + 6]);
                    acc[i][j] = m;
                }
            }
        }

        float* __restrict__ ob = uout + (((size_t)b * NC + c) << 16);
        #pragma unroll
        for (int i = 0; i < 4; ++i) {
            float4 st;
            st.x = acc[i][0]; st.y = acc[i][1]; st.z = acc[i][2]; st.w = acc[i][3];
            *reinterpret_cast<float4*>(&ob[((ty0 + er0 + i) << 8) + tx0 + ec0]) = st;
        }
    }
}

// ------- in-place channel mix: out[b,:,p] = W^T u[b,:,p], 4 pixels per thread -------
__global__ __launch_bounds__(256) void mix_kernel(float* u, const float* __restrict__ wmat) {
    const int p4 = (blockIdx.x * 256 + threadIdx.x) << 2;  // 4 consecutive pixels
    const int b = blockIdx.y;
    float* ub = u + ((size_t)b << 21);  // b * 32 * 65536

    float4 acc[NC];
    {
        const float4 v = *reinterpret_cast<const float4*>(&ub[p4]);  // channel 0
        #pragma unroll
        for (int o = 0; o < NC; ++o) {
            const float wv = wmat[o];  // wave-uniform -> s_load
            acc[o].x = v.x * wv; acc[o].y = v.y * wv;
            acc[o].z = v.z * wv; acc[o].w = v.w * wv;
        }
    }
    #pragma unroll
    for (int i = 1; i < NC; ++i) {
        const float4 v = *reinterpret_cast<const float4*>(&ub[(i << 16) + p4]);
        #pragma unroll
        for (int o = 0; o < NC; ++o) {
            const float wv = wmat[i * NC + o];  // wave-uniform -> s_load
            acc[o].x = fmaf(v.x, wv, acc[o].x);
            acc[o].y = fmaf(v.y, wv, acc[o].y);
            acc[o].z = fmaf(v.z, wv, acc[o].z);
            acc[o].w = fmaf(v.w, wv, acc[o].w);
        }
    }
    #pragma unroll
    for (int o = 0; o < NC; ++o)
        *reinterpret_cast<float4*>(&ub[(o << 16) + p4]) = acc[o];
}

extern "C" void kernel_launch(void* const* d_in, const int* in_sizes, int n_in,
                              void* d_out, int out_size, void* d_ws, size_t ws_size,
                              hipStream_t stream) {
    const float* x  = (const float*)d_in[0];
    const float* c  = (const float*)d_in[1];
    const float* fd = (const float*)d_in[2];
    const float* fe = (const float*)d_in[3];
    const float* w  = (const float*)d_in[4];
    float* out = (float*)d_out;

    float* kd = (float*)d_ws;            // 32*49 floats
    float* ke = kd + NC * NTAPS;         // 32*49 floats

    kgen_kernel<<<dim3(NC), dim3(64), 0, stream>>>(fd, fe, kd, ke);
    cde_stencil_kernel<<<dim3(16, NC, NB), dim3(256), 0, stream>>>(x, c, kd, ke, out);
    mix_kernel<<<dim3((HH * WW) / (256 * 4), NB), dim3(256), 0, stream>>>(out, w);
}

// Round 3
// 462.444 us; speedup vs baseline: 1.1129x; 1.0915x over previous
//
#include <hip/hip_runtime.h>
#include <math.h>

#define HH 256
#define WW 256
#define NB 16
#define NC 32
#define RAD 3
#define KWID 7
#define NTAPS 49
#define TILE 64
#define CW 76      // conv staging region: TILE + 2*6
#define CH 76
#define DSTR 72    // padded row stride for dilation rows (16B-aligned)
#define BUFSZ (CH * CW + 8)   // 5784 floats = 23.1 KB (slack for OOB f4 reads)
#define BIGF 1e30f
#define FLT_MAX_C 3.402823466e+38f

// ---------------- kernel-table generation (49 taps per channel) ----------------
__global__ void kgen_kernel(const float* __restrict__ fd,
                            const float* __restrict__ fe,
                            float* __restrict__ kd,
                            float* __restrict__ ke) {
    const int c = blockIdx.x;
    const int t = threadIdx.x;
    if (t >= NTAPS) return;
    const int dy = t / KWID - RAD;
    const int dx = t % KWID - RAD;
    const double rho = sqrt((double)(dx * dx + dy * dy));
    const double th  = atan2((double)dy, (double)dx);
    const double alpha = 0.65;
    const double p  = 2.0 * alpha / (2.0 * alpha - 1.0);
    const double nu = (2.0 * alpha - 1.0) * pow(2.0 * alpha, -p);
    const double b1 = cos(th), b2 = sin(th), b3 = cos(2.0 * th), b4 = sin(2.0 * th);
    double s, F;
    s = (double)fd[c * 4 + 0] * b1 + (double)fd[c * 4 + 1] * b2
      + (double)fd[c * 4 + 2] * b3 + (double)fd[c * 4 + 3] * b4;
    F = rho * exp(-s);
    kd[c * NTAPS + t] = (float)(nu * pow(F, p));
    s = (double)fe[c * 4 + 0] * b1 + (double)fe[c * 4 + 1] * b2
      + (double)fe[c * 4 + 2] * b3 + (double)fe[c * 4 + 3] * b4;
    F = rho * exp(-s);
    ke[c * NTAPS + t] = (float)(nu * pow(F, p));
}

// -------- fused convection + dilation + erosion, per (batch, channel, 64x64 tile) --------
// Single reused LDS buffer. Tap loops are split into ky-chunks {0..3},{4..6} so at most
// 28 tap values are live at once -> fits the 6-blocks/CU register budget without spills.
__global__ __launch_bounds__(256, 6) void cde_stencil_kernel(
    const float* __restrict__ xin, const float* __restrict__ csh,
    const float* __restrict__ kdil, const float* __restrict__ kero,
    float* __restrict__ uout)
{
    __shared__ float buf[BUFSZ];

    const int tid = threadIdx.x;
    const int tileId = blockIdx.x;
    const int c = blockIdx.y;
    const int b = blockIdx.z;
    const int ty0 = (tileId >> 2) * TILE;
    const int tx0 = (tileId & 3) * TILE;

    const float cx = csh[c * 2 + 0];
    const float cy = csh[c * 2 + 1];
    const float* __restrict__ xb = xin + (((size_t)b * NC + c) << 16);

    // ---- stage 1: convection (constant per-channel shift -> constant weights/offset) ----
    const float mcx = -cx, mcy = -cy;
    const float fx0 = floorf(mcx), fy0 = floorf(mcy);
    const float wxf = mcx - fx0, wyf = mcy - fy0;
    const int IX = (int)fx0, IY = (int)fy0;
    const float w00 = (1.f - wyf) * (1.f - wxf);
    const float w01 = (1.f - wyf) * wxf;
    const float w10 = wyf * (1.f - wxf);
    const float w11 = wyf * wxf;

    for (int idx = tid; idx < CH * CW; idx += 256) {
        const int row = idx / CW;
        const int col = idx - row * CW;
        const int gy = ty0 - 6 + row;
        const int gx = tx0 - 6 + col;
        float v = -BIGF;  // dilation-stage pad value (pad of -u is +BIG)
        if (gy >= 0 && gy < HH && gx >= 0 && gx < WW) {
            const int y0 = min(max(gy + IY, 0), HH - 1);
            const int y1 = min(y0 + 1, HH - 1);
            const int x0 = min(max(gx + IX, 0), WW - 1);
            const int x1 = min(x0 + 1, WW - 1);
            const float a00 = xb[(y0 << 8) + x0];
            const float a01 = xb[(y0 << 8) + x1];
            const float a10 = xb[(y1 << 8) + x0];
            const float a11 = xb[(y1 << 8) + x1];
            v = w00 * a00 + w01 * a01 + w10 * a10 + w11 * a11;
        }
        buf[idx] = v;
    }
    __syncthreads();

    // ---- stage 2: dilation  u1 = max_ky,kx (u0 - k_dil)  on 70x70 (+2 junk cols) ----
    float acc2[5][4];
    int dc0 = 0, dr0 = 0;
    const bool act2 = (tid < 252);  // 18 col-groups (4 wide) x 14 row-strips (5 tall)
    const float* __restrict__ kdc = kdil + c * NTAPS;
    if (act2) {
        dc0 = (tid % 18) * 4;
        dr0 = (tid / 18) * 5;

        #pragma unroll
        for (int i = 0; i < 5; ++i)
            #pragma unroll
            for (int j = 0; j < 4; ++j) acc2[i][j] = -FLT_MAX_C;

        {   // chunk A: tap rows ky = 0..3, input rows rr = 0..7
            float ta[28];
            #pragma unroll
            for (int t = 0; t < 28; ++t) ta[t] = kdc[t];
            #pragma unroll
            for (int rr = 0; rr < 8; ++rr) {
                const float* rp = &buf[(dr0 + rr) * CW + dc0];
                const float4 L0 = *reinterpret_cast<const float4*>(rp);
                const float4 L1 = *reinterpret_cast<const float4*>(rp + 4);
                const float4 L2 = *reinterpret_cast<const float4*>(rp + 8);
                const float ld[12] = {L0.x, L0.y, L0.z, L0.w,
                                      L1.x, L1.y, L1.z, L1.w,
                                      L2.x, L2.y, L2.z, L2.w};
                #pragma unroll
                for (int i = 0; i < 5; ++i) {
                    const int ky = rr - i;
                    if (ky < 0 || ky > 3) continue;
                    const int kb = ky * KWID;
                    #pragma unroll
                    for (int j = 0; j < 4; ++j) {
                        float m = acc2[i][j];
                        m = fmaxf(m, fmaxf(ld[j + 0] - ta[kb + 0], ld[j + 1] - ta[kb + 1]));
                        m = fmaxf(m, fmaxf(ld[j + 2] - ta[kb + 2], ld[j + 3] - ta[kb + 3]));
                        m = fmaxf(m, fmaxf(ld[j + 4] - ta[kb + 4], ld[j + 5] - ta[kb + 5]));
                        m = fmaxf(m, ld[j + 6] - ta[kb + 6]);
                        acc2[i][j] = m;
                    }
                }
            }
        }
        {   // chunk B: tap rows ky = 4..6, input rows rr = 4..10
            float tb[21];
            #pragma unroll
            for (int t = 0; t < 21; ++t) tb[t] = kdc[28 + t];
            #pragma unroll
            for (int rr = 4; rr < 11; ++rr) {
                const float* rp = &buf[(dr0 + rr) * CW + dc0];
                const float4 L0 = *reinterpret_cast<const float4*>(rp);
                const float4 L1 = *reinterpret_cast<const float4*>(rp + 4);
                const float4 L2 = *reinterpret_cast<const float4*>(rp + 8);
                const float ld[12] = {L0.x, L0.y, L0.z, L0.w,
                                      L1.x, L1.y, L1.z, L1.w,
                                      L2.x, L2.y, L2.z, L2.w};
                #pragma unroll
                for (int i = 0; i < 5; ++i) {
                    const int ky = rr - i;
                    if (ky < 4 || ky > 6) continue;
                    const int kb = (ky - 4) * KWID;
                    #pragma unroll
                    for (int j = 0; j < 4; ++j) {
                        float m = acc2[i][j];
                        m = fmaxf(m, fmaxf(ld[j + 0] - tb[kb + 0], ld[j + 1] - tb[kb + 1]));
                        m = fmaxf(m, fmaxf(ld[j + 2] - tb[kb + 2], ld[j + 3] - tb[kb + 3]));
                        m = fmaxf(m, fmaxf(ld[j + 4] - tb[kb + 4], ld[j + 5] - tb[kb + 5]));
                        m = fmaxf(m, ld[j + 6] - tb[kb + 6]);
                        acc2[i][j] = m;
                    }
                }
            }
        }
    }
    __syncthreads();  // all stage-2 reads of buf complete -> safe to overwrite

    if (act2) {
        #pragma unroll
        for (int i = 0; i < 5; ++i) {
            const int dr = dr0 + i;
            const int gy = ty0 - 3 + dr;
            const bool rOK = (gy >= 0) && (gy < HH);
            const int gxb = tx0 - 3 + dc0;
            float4 st;
            st.x = (rOK && (gxb + 0) >= 0 && (gxb + 0) < WW) ? acc2[i][0] : BIGF;
            st.y = (rOK && (gxb + 1) >= 0 && (gxb + 1) < WW) ? acc2[i][1] : BIGF;
            st.z = (rOK && (gxb + 2) >= 0 && (gxb + 2) < WW) ? acc2[i][2] : BIGF;
            st.w = (rOK && (gxb + 3) >= 0 && (gxb + 3) < WW) ? acc2[i][3] : BIGF;
            *reinterpret_cast<float4*>(&buf[dr * DSTR + dc0]) = st;
        }
    }
    __syncthreads();

    // ---- stage 3: erosion  out = min_ky,kx (u1 + k_ero)  on the 64x64 tile ----
    {
        const float* __restrict__ kec = kero + c * NTAPS;
        const int ec0 = (tid & 15) * 4;   // 16 col-groups (4 wide)
        const int er0 = (tid >> 4) * 4;   // 16 row-strips (4 tall)

        float acc[4][4];
        #pragma unroll
        for (int i = 0; i < 4; ++i)
            #pragma unroll
            for (int j = 0; j < 4; ++j) acc[i][j] = FLT_MAX_C;

        {   // chunk A: ky = 0..3, rows rr = 0..6
            float ta[28];
            #pragma unroll
            for (int t = 0; t < 28; ++t) ta[t] = kec[t];
            #pragma unroll
            for (int rr = 0; rr < 7; ++rr) {
                const float* rp = &buf[(er0 + rr) * DSTR + ec0];
                const float4 L0 = *reinterpret_cast<const float4*>(rp);
                const float4 L1 = *reinterpret_cast<const float4*>(rp + 4);
                const float4 L2 = *reinterpret_cast<const float4*>(rp + 8);
                const float ld[12] = {L0.x, L0.y, L0.z, L0.w,
                                      L1.x, L1.y, L1.z, L1.w,
                                      L2.x, L2.y, L2.z, L2.w};
                #pragma unroll
                for (int i = 0; i < 4; ++i) {
                    const int ky = rr - i;
                    if (ky < 0 || ky > 3) continue;
                    const int kb = ky * KWID;
                    #pragma unroll
                    for (int j = 0; j < 4; ++j) {
                        float m = acc[i][j];
                        m = fminf(m, fminf(ld[j + 0] + ta[kb + 0], ld[j + 1] + ta[kb + 1]));
                        m = fminf(m, fminf(ld[j + 2] + ta[kb + 2], ld[j + 3] + ta[kb + 3]));
                        m = fminf(m, fminf(ld[j + 4] + ta[kb + 4], ld[j + 5] + ta[kb + 5]));
                        m = fminf(m, ld[j + 6] + ta[kb + 6]);
                        acc[i][j] = m;
                    }
                }
            }
        }
        {   // chunk B: ky = 4..6, rows rr = 4..9
            float tb[21];
            #pragma unroll
            for (int t = 0; t < 21; ++t) tb[t] = kec[28 + t];
            #pragma unroll
            for (int rr = 4; rr < 10; ++rr) {
                const float* rp = &buf[(er0 + rr) * DSTR + ec0];
                const float4 L0 = *reinterpret_cast<const float4*>(rp);
                const float4 L1 = *reinterpret_cast<const float4*>(rp + 4);
                const float4 L2 = *reinterpret_cast<const float4*>(rp + 8);
                const float ld[12] = {L0.x, L0.y, L0.z, L0.w,
                                      L1.x, L1.y, L1.z, L1.w,
                                      L2.x, L2.y, L2.z, L2.w};
                #pragma unroll
                for (int i = 0; i < 4; ++i) {
                    const int ky = rr - i;
                    if (ky < 4 || ky > 6) continue;
                    const int kb = (ky - 4) * KWID;
                    #pragma unroll
                    for (int j = 0; j < 4; ++j) {
                        float m = acc[i][j];
                        m = fminf(m, fminf(ld[j + 0] + tb[kb + 0], ld[j + 1] + tb[kb + 1]));
                        m = fminf(m, fminf(ld[j + 2] + tb[kb + 2], ld[j + 3] + tb[kb + 3]));
                        m = fminf(m, fminf(ld[j + 4] + tb[kb + 4], ld[j + 5] + tb[kb + 5]));
                        m = fminf(m, ld[j + 6] + tb[kb + 6]);
                        acc[i][j] = m;
                    }
                }
            }
        }

        float* __restrict__ ob = uout + (((size_t)b * NC + c) << 16);
        #pragma unroll
        for (int i = 0; i < 4; ++i) {
            float4 st;
            st.x = acc[i][0]; st.y = acc[i][1]; st.z = acc[i][2]; st.w = acc[i][3];
            *reinterpret_cast<float4*>(&ob[((ty0 + er0 + i) << 8) + tx0 + ec0]) = st;
        }
    }
}

// ------- in-place channel mix: out[b,:,p] = W^T u[b,:,p], register-lean -------
// One pixel per thread; only one input channel value live at a time (acc[32] ~ 40 VGPRs).
__global__ __launch_bounds__(256) void mix_kernel(float* u, const float* __restrict__ wmat) {
    const int p = blockIdx.x * 256 + threadIdx.x;
    const int b = blockIdx.y;
    float* ub = u + ((size_t)b << 21);  // b * 32 * 65536

    float acc[NC];
    {
        const float v = ub[p];  // channel 0
        #pragma unroll
        for (int o = 0; o < NC; ++o) acc[o] = v * wmat[o];
    }
    #pragma unroll
    for (int i = 1; i < NC; ++i) {
        const float v = ub[(i << 16) + p];
        #pragma unroll
        for (int o = 0; o < NC; ++o)
            acc[o] = fmaf(v, wmat[i * NC + o], acc[o]);  // wave-uniform weights -> s_load
    }
    #pragma unroll
    for (int o = 0; o < NC; ++o) ub[(o << 16) + p] = acc[o];
}

extern "C" void kernel_launch(void* const* d_in, const int* in_sizes, int n_in,
                              void* d_out, int out_size, void* d_ws, size_t ws_size,
                              hipStream_t stream) {
    const float* x  = (const float*)d_in[0];
    const float* c  = (const float*)d_in[1];
    const float* fd = (const float*)d_in[2];
    const float* fe = (const float*)d_in[3];
    const float* w  = (const float*)d_in[4];
    float* out = (float*)d_out;

    float* kd = (float*)d_ws;            // 32*49 floats
    float* ke = kd + NC * NTAPS;         // 32*49 floats

    kgen_kernel<<<dim3(NC), dim3(64), 0, stream>>>(fd, fe, kd, ke);
    cde_stencil_kernel<<<dim3(16, NC, NB), dim3(256), 0, stream>>>(x, c, kd, ke, out);
    mix_kernel<<<dim3((HH * WW) / 256, NB), dim3(256), 0, stream>>>(out, w);
}